// Round 8
// baseline (284.464 us; speedup 1.0000x reference)
//
#include <hip/hip_runtime.h>
#include <hip/hip_bf16.h>

// WhaleAttention: B=2, N=2048, C=1024, H=16, D=64, SCALE=1/8
// R7: fix R6's load-imbalance (288 double-length kp blocks ~1.1/CU ->
// 13.9% occupancy tail). Uniform-work 1D grid, every block = one unit
// (128x128xK1024 == 128x64xK2048):
//   [0,256)    q   128x128 K=1024
//   [256,768)  kp  128x64  K=2048   (512 blocks)
//   [768,1024) v^T 128x128 K=1024
//   [1024,1056) c  128x64  K=2048   (cols 1024..1039 valid)
// 1056 blocks = 4.1/CU, no junk, no tail. Inner loop/barriers = R5/R6.
// attn = R2-best (77us), gemm_out / cast_all / compute_wuv unchanged.

typedef short bf16x8 __attribute__((ext_vector_type(8)));
typedef float f32x4 __attribute__((ext_vector_type(4)));

#define BB 2
#define NN 2048
#define CC 1024
#define HH 16
#define DD 64
#define MM (BB * NN)      // 4096 rows
#define SC2E 0.18033688f  // SCALE * log2(e)

__device__ __forceinline__ unsigned short f2bf(float f) {
    union { float f; unsigned int u; } x; x.f = f;
    unsigned int r = x.u + 0x7FFFu + ((x.u >> 16) & 1u);
    return (unsigned short)(r >> 16);
}

__device__ __forceinline__ float bf2f(unsigned short s) {
    union { unsigned int u; float f; } x; x.u = ((unsigned int)s) << 16;
    return x.f;
}

__device__ __forceinline__ unsigned int pk2(float a, float b) {
    __hip_bfloat162 h = __float22bfloat162_rn(make_float2(a, b));
    unsigned int u; __builtin_memcpy(&u, &h, 4); return u;
}

typedef __attribute__((address_space(1))) const unsigned int* gas1_t;
typedef __attribute__((address_space(3))) unsigned int* las3_t;

__device__ __forceinline__ void gload_lds16(const unsigned short* g, unsigned short* l) {
    __builtin_amdgcn_global_load_lds((gas1_t)g, (las3_t)l, 16, 0, 0);
}

// ---------------------------------------------------------------- wuv kernel
// wkpb rows 1024+h = SC2E * [u_h @ Wk_h | v_h @ Wpos_h]  (bf16, 2048 wide)
// cub[h] = SC2E * sum_d u[h,d]*bk[h*64+d]
__global__ __launch_bounds__(256) void compute_wuv(const float* __restrict__ Wk,
                                                   const float* __restrict__ Wpos,
                                                   const float* __restrict__ pbu,
                                                   const float* __restrict__ pbv,
                                                   const float* __restrict__ bk,
                                                   unsigned short* __restrict__ wkpb,
                                                   float* __restrict__ cub) {
    const int gid = blockIdx.x * 256 + threadIdx.x;   // 0..32767
    const int h = gid >> 11;                          // 16 heads
    const int col = gid & 2047;
    const float* Wsrc = (col < 1024) ? Wk : Wpos;
    const float* uv = (col < 1024) ? pbu : pbv;
    const int c = col & 1023;
    float acc = 0.f;
#pragma unroll 8
    for (int d = 0; d < 64; ++d)
        acc += uv[h * 64 + d] * Wsrc[(size_t)(h * 64 + d) * 1024 + c];
    wkpb[(size_t)(1024 + h) * 2048 + col] = f2bf(acc * SC2E);
    if (gid < 16) {
        float s = 0.f;
        for (int d = 0; d < 64; ++d) s += pbu[gid * 64 + d] * bk[gid * 64 + d];
        cub[gid] = s * SC2E;
    }
}

// ---------------------------------------------------------------- cast kernel
// All source rows are 1024 f32. dst short-offset = row*stride + colOff + col.
struct CastArgs {
    const float* src[7];
    unsigned short* dst[7];
    int stride[7];
    int colOff[7];
    int n4[7];
};
__global__ __launch_bounds__(256) void cast_all(CastArgs a) {
    const int seg = blockIdx.y;
    const int i = blockIdx.x * 256 + threadIdx.x;
    if (i >= a.n4[seg]) return;
    float4 v = ((const float4*)a.src[seg])[i];
    uint2 u;
    u.x = pk2(v.x, v.y);
    u.y = pk2(v.z, v.w);
    const int row = i >> 8, c4 = (i & 255) * 4;
    *(uint2*)&a.dst[seg][(size_t)row * a.stride[seg] + a.colOff[seg] + c4] = u;
}

// ---------------------------------------------------------------- fused GEMM
// 1D uniform-work grid (see header). BK=64 as two [*][32] slabs.
struct GemmBatch {
    const unsigned short* hsp;   // A, lda=2048
    const unsigned short* wq;    // ldb=1024
    const unsigned short* wkp;   // ldb=2048 (rows 1024.. = wuv)
    const unsigned short* wv;    // ldb=1024
    unsigned short* q;
    unsigned short* kp;
    unsigned short* vt;
    const float* bq;
    const float* bk;
    const float* bv;
    float* cbp;
    const float* cub;
};
__global__ __launch_bounds__(256) void gemm_qkvp(GemmBatch g) {
    __shared__ unsigned short Sh[2 * 128 * 64];   // As(2 slabs)|Bs(2 slabs); Tr reuse
    unsigned short* As = Sh;              // A slab kk at kk*4096 (128x32)
    unsigned short* Bs = Sh + 128 * 64;

    const int bid = blockIdx.x;
    int kind, m0, n0, K;                  // kind: 0=q 1=kp 2=v 3=c
    if (bid < 256)       { kind = 0; m0 = (bid & 31) * 128;  n0 = (bid >> 5) * 128; K = 1024; }
    else if (bid < 768)  { int i2 = bid - 256;  kind = 1; m0 = (i2 & 31) * 128; n0 = (i2 >> 5) * 64; K = 2048; }
    else if (bid < 1024) { int i3 = bid - 768;  kind = 2; m0 = (i3 & 31) * 128; n0 = (i3 >> 5) * 128; K = 1024; }
    else                 { int i4 = bid - 1024; kind = 3; m0 = i4 * 128;        n0 = 1024;            K = 2048; }
    const bool wide = (kind == 0) || (kind == 2);   // BN=128 vs 64

    const unsigned short* __restrict__ A = g.hsp;
    const unsigned short* __restrict__ B = (kind == 0) ? g.wq : (kind == 2) ? g.wv : g.wkp;
    const int lda = 2048, ldb = wide ? ((kind == 0) ? 1024 : 1024) : 2048;

    const int t = threadIdx.x;
    const int w = t >> 6, lane = t & 63, l15 = lane & 15, quad = lane >> 4;
    const int wm = (w >> 1) * 64;
    const int wn = wide ? (w & 1) * 64 : (w & 1) * 32;
    const int NJ = wide ? 4 : 2;

    f32x4 acc[4][4];
#pragma unroll
    for (int i = 0; i < 4; ++i)
#pragma unroll
        for (int j = 0; j < 4; ++j)
#pragma unroll
            for (int r = 0; r < 4; ++r) acc[i][j][r] = 0.f;

    for (int kb = 0; kb < K; kb += 64) {
        __syncthreads();
        // A: 128x64 as two [128][32] slabs (1024 chunks of 16B)
#pragma unroll
        for (int j = 0; j < 4; ++j) {
            const int id = j * 256 + t;
            const int half = id >> 9, id9 = id & 511;
            const int row = id9 >> 2, c4 = (id9 & 3) * 8;
            gload_lds16(&A[(size_t)(m0 + row) * lda + kb + half * 32 + c4],
                        &As[half * 4096 + id9 * 8]);
        }
        if (wide) {
            // B: 128x64 as two [128][32] slabs
#pragma unroll
            for (int j = 0; j < 4; ++j) {
                const int id = j * 256 + t;
                const int half = id >> 9, id9 = id & 511;
                const int row = id9 >> 2, c4 = (id9 & 3) * 8;
                gload_lds16(&B[(size_t)(n0 + row) * ldb + kb + half * 32 + c4],
                            &Bs[half * 4096 + id9 * 8]);
            }
        } else {
            // B: 64x64 as two [64][32] slabs (512 chunks)
#pragma unroll
            for (int j = 0; j < 2; ++j) {
                const int id = j * 256 + t;
                const int half = id >> 8, id8 = id & 255;
                const int row = id8 >> 2, c4 = (id8 & 3) * 8;
                gload_lds16(&B[(size_t)(n0 + row) * ldb + kb + half * 32 + c4],
                            &Bs[half * 2048 + id8 * 8]);
            }
        }
        __syncthreads();
#pragma unroll
        for (int kk = 0; kk < 2; ++kk) {
            bf16x8 af[4], bfr[4];
#pragma unroll
            for (int i = 0; i < 4; ++i)
                af[i] = *(const bf16x8*)&As[kk * 4096 + (wm + i * 16 + l15) * 32 + quad * 8];
            if (wide) {
#pragma unroll
                for (int j = 0; j < 4; ++j)
                    bfr[j] = *(const bf16x8*)&Bs[kk * 4096 + (wn + j * 16 + l15) * 32 + quad * 8];
#pragma unroll
                for (int i = 0; i < 4; ++i)
#pragma unroll
                    for (int j = 0; j < 4; ++j)
                        acc[i][j] = __builtin_amdgcn_mfma_f32_16x16x32_bf16(af[i], bfr[j], acc[i][j], 0, 0, 0);
            } else {
#pragma unroll
                for (int j = 0; j < 2; ++j)
                    bfr[j] = *(const bf16x8*)&Bs[kk * 2048 + (wn + j * 16 + l15) * 32 + quad * 8];
#pragma unroll
                for (int i = 0; i < 4; ++i)
#pragma unroll
                    for (int j = 0; j < 2; ++j)
                        acc[i][j] = __builtin_amdgcn_mfma_f32_16x16x32_bf16(af[i], bfr[j], acc[i][j], 0, 0, 0);
            }
        }
    }

    if (kind == 0) {
        // q epilogue: (acc+bq)*SC2E, bf16
#pragma unroll
        for (int i = 0; i < 4; ++i)
#pragma unroll
            for (int j = 0; j < 4; ++j) {
                const int col = n0 + wn + j * 16 + l15;
                const int row_base = m0 + wm + i * 16 + quad * 4;
                const float bc = g.bq[col];
#pragma unroll
                for (int r = 0; r < 4; ++r)
                    g.q[(size_t)(row_base + r) * CC + col] = f2bf((acc[i][j][r] + bc) * SC2E);
            }
    } else if (kind == 1) {
        // kp epilogue: acc + bk, bf16 (BN=64)
#pragma unroll
        for (int i = 0; i < 4; ++i)
#pragma unroll
            for (int j = 0; j < 2; ++j) {
                const int col = n0 + wn + j * 16 + l15;
                const int row_base = m0 + wm + i * 16 + quad * 4;
                const float bc = g.bk[col];
#pragma unroll
                for (int r = 0; r < 4; ++r)
                    g.kp[(size_t)(row_base + r) * CC + col] = f2bf(acc[i][j][r] + bc);
            }
    } else if (kind == 3) {
        // c epilogue: cols 1024..1039 (even waves, j=0, h=l15)
        if ((w & 1) == 0) {
            const int bI = (m0 + wm) >> 11;
            const int nbase = (m0 + wm) & 2047;
            const float cu = g.cub[l15];
#pragma unroll
            for (int i = 0; i < 4; ++i)
#pragma unroll
                for (int r = 0; r < 4; ++r) {
                    const int nseq = nbase + i * 16 + quad * 4 + r;
                    g.cbp[((size_t)(bI * 16 + l15)) * 2048 + nseq] = acc[i][0][r] + cu;
                }
        }
    } else {
        // v^T epilogue: per-wave 16-col chunks through LDS, then
        // 128B-contiguous dwordx4 stores to vt (B,H,D,N).
        __syncthreads();    // all waves done reading As/Bs fragments
        unsigned short* Tr = &Sh[w * 1152];   // 16 cols x stride 72
        const int bI = (m0 + wm) >> 11, nseq0 = (m0 + wm) & 2047;
        const int colL = lane >> 3;           // 0..7
        const int mL = (lane & 7) * 8;        // 0..56
#pragma unroll
        for (int j = 0; j < 4; ++j) {
            const int col = n0 + wn + j * 16 + l15;
            const float bc = g.bv[col];
#pragma unroll
            for (int i = 0; i < 4; ++i) {
                uint2 pk;
                pk.x = pk2(acc[i][j][0] + bc, acc[i][j][1] + bc);
                pk.y = pk2(acc[i][j][2] + bc, acc[i][j][3] + bc);
                *(uint2*)&Tr[l15 * 72 + i * 16 + quad * 4] = pk;
            }
            // same-wave DS ops are in-order; reads below see the writes above
#pragma unroll
            for (int p = 0; p < 2; ++p) {
                const int cl = p * 8 + colL;
                uint4 vv = *(const uint4*)&Tr[cl * 72 + mL];
                const int gcol = n0 + wn + j * 16 + cl;
                const int hh = gcol >> 6, dd = gcol & 63;
                *(uint4*)&g.vt[((size_t)(bI * 16 + hh) * 64 + dd) * 2048 + nseq0 + mL] = vv;
            }
        }
    }
}

// ---------------------------------------------------------------- attention
// R2-best shape (77us measured): (qt,h,b) -> 128 q rows, 8 waves x 16 q.
// KVBLK=128, double-buffered K/V staging, prefetch after the single per-iter
// barrier. Per tile: two 64-key halves through {QK^T (c-init), exp2, Ps
// roundtrip, PV} reusing s regs / Ps buffer. setprio(1) around MFMA.
__global__ __launch_bounds__(512) void attn_kernel(const unsigned short* __restrict__ q,
                                                   const unsigned short* __restrict__ kp,
                                                   const unsigned short* __restrict__ vt,
                                                   const float* __restrict__ cb,
                                                   unsigned short* __restrict__ att) {
    __shared__ unsigned short Ks[2][128 * 64];   // [key][d], XOR-swizzled
    __shared__ unsigned short Vs[2][64 * 128];   // [d][key], XOR-swizzled
    __shared__ unsigned short Ps[8][16 * 64];    // per-wave P round-trip

    const int t = threadIdx.x;
    const int w = t >> 6, lane = t & 63, l15 = lane & 15, quad = lane >> 4;
    const int qt = blockIdx.x, h = blockIdx.y, b = blockIdx.z;
    const int e3 = l15 & 7;

    // Q fragment: 16 q rows per wave (registers, loaded once)
    bf16x8 qf[2];
    {
        const int qrow = qt * 128 + w * 16 + l15;
        const size_t qoff = ((size_t)(b * NN + qrow) * HH + h) * DD;
#pragma unroll
        for (int c2 = 0; c2 < 2; ++c2)
            qf[c2] = *(const bf16x8*)&q[qoff + c2 * 32 + quad * 8];
    }

    f32x4 oT[4];
    float l_lane = 0.f;
#pragma unroll
    for (int db = 0; db < 4; ++db)
#pragma unroll
        for (int r = 0; r < 4; ++r) oT[db][r] = 0.f;

    const size_t kbase = (size_t)b * NN * CC + (size_t)h * DD;
    const size_t vbase = (size_t)(b * HH + h) * DD * NN;
    const size_t cbase = (size_t)(b * HH + h) * NN;

    // staging maps (kt-invariant): 512 threads x 2 segments, 16B each.
    int krow[2], kgc[2], vd[2], vgc[2];
#pragma unroll
    for (int j = 0; j < 2; ++j) {
        const int id = j * 512 + t;
        krow[j] = id >> 3;
        kgc[j] = ((id & 7) ^ (krow[j] & 7)) * 8;
        vd[j] = id >> 4;
        vgc[j] = ((id & 15) ^ (vd[j] & 7)) * 8;
    }

    // prologue: stage kt=0 into buffer 0
#pragma unroll
    for (int j = 0; j < 2; ++j) {
        const int id = j * 512 + t;
        gload_lds16(&kp[kbase + (size_t)krow[j] * CC + kgc[j]], &Ks[0][id * 8]);
        gload_lds16(&vt[vbase + (size_t)vd[j] * NN + vgc[j]], &Vs[0][id * 8]);
    }

    for (int kt = 0; kt < NN / 128; ++kt) {
        const int cur = kt & 1;
        __syncthreads();   // drains prefetch issued last iter (full iter of cover)
        if (kt + 1 < NN / 128) {
#pragma unroll
            for (int j = 0; j < 2; ++j) {
                const int id = j * 512 + t;
                gload_lds16(&kp[kbase + (size_t)((kt + 1) * 128 + krow[j]) * CC + kgc[j]],
                            &Ks[cur ^ 1][id * 8]);
                gload_lds16(&vt[vbase + (size_t)vd[j] * NN + (kt + 1) * 128 + vgc[j]],
                            &Vs[cur ^ 1][id * 8]);
            }
        }

        // c-init for the whole 128-key tile
        f32x4 c8r[8];
#pragma unroll
        for (int t8 = 0; t8 < 8; ++t8)
            c8r[t8] = *(const f32x4*)&cb[cbase + kt * 128 + t8 * 16 + quad * 4];

#pragma unroll
        for (int half = 0; half < 2; ++half) {
            // S^T (64 keys x 16 q per wave), c-initialized
            f32x4 s[4];
#pragma unroll
            for (int t4 = 0; t4 < 4; ++t4) s[t4] = c8r[half * 4 + t4];

            __builtin_amdgcn_s_setprio(1);
#pragma unroll
            for (int t4 = 0; t4 < 4; ++t4) {
                const int row = half * 64 + t4 * 16 + l15;
#pragma unroll
                for (int c2 = 0; c2 < 2; ++c2) {
                    bf16x8 kf = *(const bf16x8*)&Ks[cur][row * 64 + (((c2 * 4 + quad) ^ e3) * 8)];
                    s[t4] = __builtin_amdgcn_mfma_f32_16x16x32_bf16(kf, qf[c2], s[t4], 0, 0, 0);
                }
            }
            __builtin_amdgcn_s_setprio(0);

            // fixed-base exp2 softmax; l reduced once at the end
            float rs = 0.f;
#pragma unroll
            for (int t4 = 0; t4 < 4; ++t4)
#pragma unroll
                for (int r = 0; r < 4; ++r) {
                    float pv = exp2f(s[t4][r]);
                    s[t4][r] = pv;
                    rs += pv;
                }
            l_lane += rs;
            // Ps store: XOR-swizzle whole 8-short blocks by (l15&7), no pad.
#pragma unroll
            for (int t4 = 0; t4 < 4; ++t4) {
                uint2 pk;
                pk.x = pk2(s[t4][0], s[t4][1]);
                pk.y = pk2(s[t4][2], s[t4][3]);
                const int blk = t4 * 2 + (quad >> 1);
                *(uint2*)&Ps[w][l15 * 64 + ((blk ^ e3) * 8) + (quad & 1) * 4] = pk;
            }
            // no barrier: Ps[w] wave-private; same-wave DS ops in-order

            // O^T += V^T · P  (keys half*64 .. half*64+63)
            __builtin_amdgcn_s_setprio(1);
#pragma unroll
            for (int c2 = 0; c2 < 2; ++c2) {
                bf16x8 pf = *(const bf16x8*)&Ps[w][l15 * 64 + (((c2 * 4 + quad) ^ e3) * 8)];
#pragma unroll
                for (int db = 0; db < 4; ++db) {
                    bf16x8 vf = *(const bf16x8*)&Vs[cur][(db * 16 + l15) * 128 +
                                                         (((half * 8 + c2 * 4 + quad) ^ e3) * 8)];
                    oT[db] = __builtin_amdgcn_mfma_f32_16x16x32_bf16(vf, pf, oT[db], 0, 0, 0);
                }
            }
            __builtin_amdgcn_s_setprio(0);
        }
    }

    // epilogue: normalize and write bf16 (B,N,H,D)
    float l = l_lane;
    l += __shfl_xor(l, 16);
    l += __shfl_xor(l, 32);
    const float inv = 1.f / l;
    const int qrow = qt * 128 + w * 16 + l15;
    const size_t ob = ((size_t)(b * NN + qrow) * HH + h) * DD;
#pragma unroll
    for (int db = 0; db < 4; ++db) {
        uint2 pk;
        pk.x = pk2(oT[db][0] * inv, oT[db][1] * inv);
        pk.y = pk2(oT[db][2] * inv, oT[db][3] * inv);
        *(uint2*)&att[ob + db * 16 + quad * 4] = pk;
    }
}

// ---------------------------------------------------------------- out GEMM
// out fp32 = att·Wo^T + bo. 128x64 tile -> 512 blocks = 2/CU. (original)
__global__ __launch_bounds__(256) void gemm_out(const unsigned short* __restrict__ A,
                                                const unsigned short* __restrict__ B,
                                                float* __restrict__ out,
                                                const float* __restrict__ bias) {
    constexpr int K = CC;
    __shared__ unsigned short As[128 * 32];
    __shared__ unsigned short Bs[64 * 32];
    const int t = threadIdx.x;
    const int w = t >> 6, lane = t & 63, l15 = lane & 15, quad = lane >> 4;
    const int m0 = blockIdx.x * 128, n0 = blockIdx.y * 64;
    const int wm = (w >> 1) * 64, wn = (w & 1) * 32;

    f32x4 acc[4][2];
#pragma unroll
    for (int i = 0; i < 4; ++i)
#pragma unroll
        for (int j = 0; j < 2; ++j)
#pragma unroll
            for (int r = 0; r < 4; ++r) acc[i][j][r] = 0.f;

    for (int kb = 0; kb < K; kb += 32) {
        __syncthreads();
#pragma unroll
        for (int j = 0; j < 2; ++j) {
            int id = j * 256 + t;
            int row = id >> 2, c4 = (id & 3) * 8;
            gload_lds16(&A[(size_t)(m0 + row) * K + kb + c4], &As[id * 8]);
        }
        {
            int row = t >> 2, c4 = (t & 3) * 8;
            gload_lds16(&B[(size_t)(n0 + row) * K + kb + c4], &Bs[t * 8]);
        }
        __syncthreads();
        bf16x8 af[4], bfr[2];
#pragma unroll
        for (int i = 0; i < 4; ++i)
            af[i] = *(const bf16x8*)&As[(wm + i * 16 + l15) * 32 + quad * 8];
#pragma unroll
        for (int j = 0; j < 2; ++j)
            bfr[j] = *(const bf16x8*)&Bs[(wn + j * 16 + l15) * 32 + quad * 8];
#pragma unroll
        for (int i = 0; i < 4; ++i)
#pragma unroll
            for (int j = 0; j < 2; ++j)
                acc[i][j] = __builtin_amdgcn_mfma_f32_16x16x32_bf16(af[i], bfr[j], acc[i][j], 0, 0, 0);
    }

#pragma unroll
    for (int i = 0; i < 4; ++i)
#pragma unroll
        for (int j = 0; j < 2; ++j) {
            const int col = n0 + wn + j * 16 + l15;
            const int row_base = m0 + wm + i * 16 + quad * 4;
            const float bc = bias[col];
#pragma unroll
            for (int r = 0; r < 4; ++r)
                out[(size_t)(row_base + r) * CC + col] = acc[i][j][r] + bc;
        }
}

// ---------------------------------------------------------------- launch
extern "C" void kernel_launch(void* const* d_in, const int* in_sizes, int n_in,
                              void* d_out, int out_size, void* d_ws, size_t ws_size,
                              hipStream_t stream) {
    const float* hs   = (const float*)d_in[0];
    const float* pos  = (const float*)d_in[1];
    const float* Wq   = (const float*)d_in[2];
    const float* bq   = (const float*)d_in[3];
    const float* Wk   = (const float*)d_in[4];
    const float* bk   = (const float*)d_in[5];
    const float* Wv   = (const float*)d_in[6];
    const float* bv   = (const float*)d_in[7];
    const float* Wpos = (const float*)d_in[8];
    const float* pbu  = (const float*)d_in[9];
    const float* pbv  = (const float*)d_in[10];
    const float* Wo   = (const float*)d_in[11];
    const float* bo   = (const float*)d_in[12];
    float* out = (float*)d_out;

    const size_t nHS = (size_t)MM * CC;     // 4096*1024
    const size_t nW  = (size_t)CC * CC;

    unsigned short* p = (unsigned short*)d_ws;
    unsigned short* hspb = p;            p += (size_t)MM * 2048;        // [hs|pos]
    unsigned short* wqb  = p;            p += nW;
    unsigned short* wkpb = p;            p += (size_t)1152 * 2048;      // [Wk|Wpos]+wuv
    unsigned short* wvb  = p;            p += nW;
    unsigned short* wob  = p;            p += nW;
    unsigned short* qsb  = p;            p += nHS;
    unsigned short* kpb  = p;            p += nHS;
    unsigned short* vtb  = p;            p += nHS;
    float* cb  = (float*)p;              p += (size_t)BB * HH * NN * 2;
    float* cub = (float*)p;              p += 32;
    unsigned short* attb = hspb;         // alias: hspb dead after gemm_qkvp

    compute_wuv<<<128, 256, 0, stream>>>(Wk, Wpos, pbu, pbv, bk, wkpb, cub);

    CastArgs ca;
    ca.src[0] = hs;   ca.dst[0] = hspb; ca.stride[0] = 2048; ca.colOff[0] = 0;    ca.n4[0] = (int)(nHS / 4);
    ca.src[1] = pos;  ca.dst[1] = hspb; ca.stride[1] = 2048; ca.colOff[1] = 1024; ca.n4[1] = (int)(nHS / 4);
    ca.src[2] = Wq;   ca.dst[2] = wqb;  ca.stride[2] = 1024; ca.colOff[2] = 0;    ca.n4[2] = (int)(nW / 4);
    ca.src[3] = Wk;   ca.dst[3] = wkpb; ca.stride[3] = 2048; ca.colOff[3] = 0;    ca.n4[3] = (int)(nW / 4);
    ca.src[4] = Wpos; ca.dst[4] = wkpb; ca.stride[4] = 2048; ca.colOff[4] = 1024; ca.n4[4] = (int)(nW / 4);
    ca.src[5] = Wv;   ca.dst[5] = wvb;  ca.stride[5] = 1024; ca.colOff[5] = 0;    ca.n4[5] = (int)(nW / 4);
    ca.src[6] = Wo;   ca.dst[6] = wob;  ca.stride[6] = 1024; ca.colOff[6] = 0;    ca.n4[6] = (int)(nW / 4);
    dim3 cgrid((unsigned)(nHS / 4 / 256), 7);
    cast_all<<<cgrid, 256, 0, stream>>>(ca);

    GemmBatch gb;
    gb.hsp = hspb; gb.wq = wqb; gb.wkp = wkpb; gb.wv = wvb;
    gb.q = qsb; gb.kp = kpb; gb.vt = vtb;
    gb.bq = bq; gb.bk = bk; gb.bv = bv;
    gb.cbp = cb; gb.cub = cub;
    gemm_qkvp<<<1056, 256, 0, stream>>>(gb);

    dim3 agrid(NN / 128, HH, BB);
    attn_kernel<<<agrid, 512, 0, stream>>>(qsb, kpb, vtb, cb, attb);

    dim3 ogrid(MM / 128, CC / 64);
    gemm_out<<<ogrid, 256, 0, stream>>>(attb, wob, out, bo);
}

// Round 9
// 274.806 us; speedup vs baseline: 1.0351x; 1.0351x over previous
//
#include <hip/hip_runtime.h>
#include <hip/hip_bf16.h>

// WhaleAttention: B=2, N=2048, C=1024, H=16, D=64, SCALE=1/8
// R8: full revert to R5 (best measured, 257.45us: separate k/p GEMMs with
// lda=1024, BK=64 qkvp, fuse_kpc, original gemm_out, R2 attn) — the R6/R7
// kp-fusion arc regressed (narrow-tile kp + 4KB-stride A rows).
// ONE surgical attn change: c-init loads pipelined one K-tile ahead
// (ping-pong cA/cB registers, explicit even/odd tile bodies) so the
// post-barrier L2 latency is covered by a full tile of compute instead of
// stalling the first QK MFMA of every tile.

typedef short bf16x8 __attribute__((ext_vector_type(8)));
typedef float f32x4 __attribute__((ext_vector_type(4)));

#define BB 2
#define NN 2048
#define CC 1024
#define HH 16
#define DD 64
#define MM (BB * NN)      // 4096 rows
#define SC2E 0.18033688f  // SCALE * log2(e)

__device__ __forceinline__ unsigned short f2bf(float f) {
    union { float f; unsigned int u; } x; x.f = f;
    unsigned int r = x.u + 0x7FFFu + ((x.u >> 16) & 1u);
    return (unsigned short)(r >> 16);
}

__device__ __forceinline__ float bf2f(unsigned short s) {
    union { unsigned int u; float f; } x; x.u = ((unsigned int)s) << 16;
    return x.f;
}

__device__ __forceinline__ unsigned int pk2(float a, float b) {
    __hip_bfloat162 h = __float22bfloat162_rn(make_float2(a, b));
    unsigned int u; __builtin_memcpy(&u, &h, 4); return u;
}

typedef __attribute__((address_space(1))) const unsigned int* gas1_t;
typedef __attribute__((address_space(3))) unsigned int* las3_t;

__device__ __forceinline__ void gload_lds16(const unsigned short* g, unsigned short* l) {
    __builtin_amdgcn_global_load_lds((gas1_t)g, (las3_t)l, 16, 0, 0);
}

// ---------------------------------------------------------------- cast kernel
struct CastArgs {
    const float* src[7];
    unsigned short* dst[7];
    int n4[7];
};
__global__ __launch_bounds__(256) void cast_all(CastArgs a) {
    const int seg = blockIdx.y;
    const int i = blockIdx.x * 256 + threadIdx.x;
    if (i >= a.n4[seg]) return;
    float4 v = ((const float4*)a.src[seg])[i];
    uint2 u;
    u.x = pk2(v.x, v.y);
    u.y = pk2(v.z, v.w);
    ((uint2*)a.dst[seg])[i] = u;
}

// ---------------------------------------------------------------- batched GEMM
// z=0: q (bf16, (acc+bq)*SC2E), z=1: k (+bk), z=2: v transposed (B,H,D,N)
// via LDS transpose epilogue, z=3: p (plain). 128x128 tile.
// BK=64 (16 K-iters, 2 barriers each). LDS = two [128][32] slabs per
// operand (m97 bank pattern preserved).
struct GemmBatch {
    const unsigned short* A[4];
    const unsigned short* B[4];
    unsigned short* out[4];
    const float* bias[4];
};
__global__ __launch_bounds__(256) void gemm_qkvp(GemmBatch g) {
    constexpr int K = CC;
    __shared__ unsigned short Sh[2 * 128 * 64];   // As(2 slabs) | Bs(2 slabs); Tr reuse
    unsigned short* As = Sh;              // [kk][row][32]: slab kk at kk*4096
    unsigned short* Bs = Sh + 128 * 64;
    const int z = blockIdx.z;
    const unsigned short* __restrict__ A = g.A[z];
    const unsigned short* __restrict__ B = g.B[z];
    unsigned short* __restrict__ out = g.out[z];
    const float* __restrict__ bias = g.bias[z];

    const int t = threadIdx.x;
    const int w = t >> 6, lane = t & 63, l15 = lane & 15, quad = lane >> 4;
    const int m0 = blockIdx.x * 128, n0 = blockIdx.y * 128;
    const int wm = (w >> 1) * 64, wn = (w & 1) * 64;

    f32x4 acc[4][4];
#pragma unroll
    for (int i = 0; i < 4; ++i)
#pragma unroll
        for (int j = 0; j < 4; ++j)
#pragma unroll
            for (int r = 0; r < 4; ++r) acc[i][j][r] = 0.f;

    for (int kb = 0; kb < K; kb += 64) {
        __syncthreads();
        // stage 128x64 per operand as two [128][32] slabs.
        // 1024 chunks of 16B per operand; 256 threads x 4.
#pragma unroll
        for (int j = 0; j < 4; ++j) {
            const int id = j * 256 + t;           // 0..1023
            const int half = id >> 9;             // col-slab 0/1
            const int id9 = id & 511;             // within-slab chunk
            const int row = id9 >> 2, c4 = (id9 & 3) * 8;
            gload_lds16(&A[(size_t)(m0 + row) * K + kb + half * 32 + c4],
                        &As[half * 4096 + id9 * 8]);
            gload_lds16(&B[(size_t)(n0 + row) * K + kb + half * 32 + c4],
                        &Bs[half * 4096 + id9 * 8]);
        }
        __syncthreads();
#pragma unroll
        for (int kk = 0; kk < 2; ++kk) {
            bf16x8 af[4], bfr[4];
#pragma unroll
            for (int i = 0; i < 4; ++i)
                af[i] = *(const bf16x8*)&As[kk * 4096 + (wm + i * 16 + l15) * 32 + quad * 8];
#pragma unroll
            for (int j = 0; j < 4; ++j)
                bfr[j] = *(const bf16x8*)&Bs[kk * 4096 + (wn + j * 16 + l15) * 32 + quad * 8];
#pragma unroll
            for (int i = 0; i < 4; ++i)
#pragma unroll
                for (int j = 0; j < 4; ++j)
                    acc[i][j] = __builtin_amdgcn_mfma_f32_16x16x32_bf16(af[i], bfr[j], acc[i][j], 0, 0, 0);
        }
    }

    if (z != 2) {
        const float sc = (z == 0) ? SC2E : 1.f;
#pragma unroll
        for (int i = 0; i < 4; ++i)
#pragma unroll
            for (int j = 0; j < 4; ++j) {
                const int col = n0 + wn + j * 16 + l15;
                const int row_base = m0 + wm + i * 16 + quad * 4;
                const float bc = bias ? bias[col] : 0.f;
#pragma unroll
                for (int r = 0; r < 4; ++r)
                    out[(size_t)(row_base + r) * CC + col] = f2bf((acc[i][j][r] + bc) * sc);
            }
    } else {
        // v^T epilogue: per-wave 16-col chunks through LDS (reusing Sh;
        // per-wave 16x72 = 2304B, 4 waves = 9.2KB), then 128B-contiguous
        // dwordx4 stores to vt (B,H,D,N).
        __syncthreads();    // all waves done reading As/Bs fragments
        unsigned short* Tr = &Sh[w * 1152];   // 16 cols x stride 72
        const int bI = (m0 + wm) >> 11, nseq0 = (m0 + wm) & 2047;
        const int colL = lane >> 3;           // 0..7
        const int mL = (lane & 7) * 8;        // 0..56
#pragma unroll
        for (int j = 0; j < 4; ++j) {
            const int col = n0 + wn + j * 16 + l15;
            const float bc = bias[col];
#pragma unroll
            for (int i = 0; i < 4; ++i) {
                uint2 pk;
                pk.x = pk2(acc[i][j][0] + bc, acc[i][j][1] + bc);
                pk.y = pk2(acc[i][j][2] + bc, acc[i][j][3] + bc);
                *(uint2*)&Tr[l15 * 72 + i * 16 + quad * 4] = pk;
            }
            // same-wave DS ops are in-order; reads below see the writes above
#pragma unroll
            for (int p = 0; p < 2; ++p) {
                const int cl = p * 8 + colL;
                uint4 vv = *(const uint4*)&Tr[cl * 72 + mL];
                const int gcol = n0 + wn + j * 16 + cl;
                const int hh = gcol >> 6, dd = gcol & 63;
                *(uint4*)&out[((size_t)(bI * 16 + hh) * 64 + dd) * 2048 + nseq0 + mL] = vv;
            }
        }
    }
}

// ---------------------------------------------------------------- fuse kp + c
// One wave per (row, h): kp = k + p (bf16) and c = SC2E*(u·k + v·p) (fp32).
__global__ __launch_bounds__(256) void fuse_kpc(const unsigned short* __restrict__ k,
                                                const unsigned short* __restrict__ pp,
                                                const float* __restrict__ pbu,
                                                const float* __restrict__ pbv,
                                                unsigned short* __restrict__ kp,
                                                float* __restrict__ c) {
    const int gw = (blockIdx.x * 256 + threadIdx.x) >> 6;
    const int lane = threadIdx.x & 63;
    const int row = gw >> 4, h = gw & 15;          // row = b*N + n
    const size_t off = (size_t)row * CC + h * 64 + lane;
    const float kv = bf2f(k[off]), pv = bf2f(pp[off]);
    kp[off] = f2bf(kv + pv);
    float val = pbu[h * 64 + lane] * kv + pbv[h * 64 + lane] * pv;
#pragma unroll
    for (int o = 1; o < 64; o <<= 1) val += __shfl_xor(val, o);
    if (lane == 0) {
        const int b = row >> 11, n = row & 2047;
        c[((size_t)(b * HH + h)) * NN + n] = val * SC2E;
    }
}

// ---------------------------------------------------------------- attention
// R2-best shape: (qt,h,b) -> 128 q rows, 8 waves x 16 q. KVBLK=128,
// double-buffered K/V staging, prefetch after the single per-tile barrier.
// R8: c-init pipelined one tile ahead (cA even tiles / cB odd tiles,
// explicit bodies -> static register indexing; loads cross a barrier so
// latency is covered by a full tile of compute).
__global__ __launch_bounds__(512) void attn_kernel(const unsigned short* __restrict__ q,
                                                   const unsigned short* __restrict__ kp,
                                                   const unsigned short* __restrict__ vt,
                                                   const float* __restrict__ cb,
                                                   unsigned short* __restrict__ att) {
    __shared__ unsigned short Ks[2][128 * 64];   // [key][d], XOR-swizzled
    __shared__ unsigned short Vs[2][64 * 128];   // [d][key], XOR-swizzled
    __shared__ unsigned short Ps[8][16 * 64];    // per-wave P round-trip

    const int t = threadIdx.x;
    const int w = t >> 6, lane = t & 63, l15 = lane & 15, quad = lane >> 4;
    const int qt = blockIdx.x, h = blockIdx.y, b = blockIdx.z;
    const int e3 = l15 & 7;

    // Q fragment: 16 q rows per wave (registers, loaded once)
    bf16x8 qf[2];
    {
        const int qrow = qt * 128 + w * 16 + l15;
        const size_t qoff = ((size_t)(b * NN + qrow) * HH + h) * DD;
#pragma unroll
        for (int c2 = 0; c2 < 2; ++c2)
            qf[c2] = *(const bf16x8*)&q[qoff + c2 * 32 + quad * 8];
    }

    f32x4 oT[4];
    float l_lane = 0.f;
#pragma unroll
    for (int db = 0; db < 4; ++db)
#pragma unroll
        for (int r = 0; r < 4; ++r) oT[db][r] = 0.f;

    const size_t kbase = (size_t)b * NN * CC + (size_t)h * DD;
    const size_t vbase = (size_t)(b * HH + h) * DD * NN;
    const size_t cbase = (size_t)(b * HH + h) * NN;

    // staging maps (kt-invariant): 512 threads x 2 segments, 16B each.
    // K tile: 128 rows x 8 chunks; V tile: 64 d-rows x 16 chunks. XOR
    // pre-swizzle on the GLOBAL chunk (involution; LDS dest stays linear).
    int krow[2], kgc[2], vd[2], vgc[2];
#pragma unroll
    for (int j = 0; j < 2; ++j) {
        const int id = j * 512 + t;
        krow[j] = id >> 3;
        kgc[j] = ((id & 7) ^ (krow[j] & 7)) * 8;
        vd[j] = id >> 4;
        vgc[j] = ((id & 15) ^ (vd[j] & 7)) * 8;
    }

    auto STAGE = [&](int tile, int buf) {
#pragma unroll
        for (int j = 0; j < 2; ++j) {
            const int id = j * 512 + t;
            gload_lds16(&kp[kbase + (size_t)(tile * 128 + krow[j]) * CC + kgc[j]],
                        &Ks[buf][id * 8]);
            gload_lds16(&vt[vbase + (size_t)vd[j] * NN + tile * 128 + vgc[j]],
                        &Vs[buf][id * 8]);
        }
    };

    auto LOADC = [&](f32x4 (&cc)[8], int tile) {
#pragma unroll
        for (int t8 = 0; t8 < 8; ++t8)
            cc[t8] = *(const f32x4*)&cb[cbase + tile * 128 + t8 * 16 + quad * 4];
    };

    auto DOTILE = [&](int buf, const f32x4 (&cc)[8]) {
#pragma unroll
        for (int half = 0; half < 2; ++half) {
            // S^T (64 keys x 16 q per wave), c-initialized
            f32x4 s[4];
#pragma unroll
            for (int t4 = 0; t4 < 4; ++t4) s[t4] = cc[half * 4 + t4];

            __builtin_amdgcn_s_setprio(1);
#pragma unroll
            for (int t4 = 0; t4 < 4; ++t4) {
                const int row = half * 64 + t4 * 16 + l15;
#pragma unroll
                for (int c2 = 0; c2 < 2; ++c2) {
                    bf16x8 kf = *(const bf16x8*)&Ks[buf][row * 64 + (((c2 * 4 + quad) ^ e3) * 8)];
                    s[t4] = __builtin_amdgcn_mfma_f32_16x16x32_bf16(kf, qf[c2], s[t4], 0, 0, 0);
                }
            }
            __builtin_amdgcn_s_setprio(0);

            // fixed-base exp2 softmax; l reduced once at the end
            float rs = 0.f;
#pragma unroll
            for (int t4 = 0; t4 < 4; ++t4)
#pragma unroll
                for (int r = 0; r < 4; ++r) {
                    float pv = exp2f(s[t4][r]);
                    s[t4][r] = pv;
                    rs += pv;
                }
            l_lane += rs;
            // Ps store: XOR-swizzle whole 8-short blocks by (l15&7), no pad.
#pragma unroll
            for (int t4 = 0; t4 < 4; ++t4) {
                uint2 pk;
                pk.x = pk2(s[t4][0], s[t4][1]);
                pk.y = pk2(s[t4][2], s[t4][3]);
                const int blk = t4 * 2 + (quad >> 1);
                *(uint2*)&Ps[w][l15 * 64 + ((blk ^ e3) * 8) + (quad & 1) * 4] = pk;
            }
            // no barrier: Ps[w] wave-private; same-wave DS ops in-order

            // O^T += V^T · P  (keys half*64 .. half*64+63)
            __builtin_amdgcn_s_setprio(1);
#pragma unroll
            for (int c2 = 0; c2 < 2; ++c2) {
                bf16x8 pf = *(const bf16x8*)&Ps[w][l15 * 64 + (((c2 * 4 + quad) ^ e3) * 8)];
#pragma unroll
                for (int db = 0; db < 4; ++db) {
                    bf16x8 vf = *(const bf16x8*)&Vs[buf][(db * 16 + l15) * 128 +
                                                         (((half * 8 + c2 * 4 + quad) ^ e3) * 8)];
                    oT[db] = __builtin_amdgcn_mfma_f32_16x16x32_bf16(vf, pf, oT[db], 0, 0, 0);
                }
            }
            __builtin_amdgcn_s_setprio(0);
        }
    };

    // prologue: stage tile 0 into buffer 0; preload its c
    STAGE(0, 0);
    f32x4 cA[8], cB[8];
    LOADC(cA, 0);

    // 16 tiles as 8 even/odd pairs; barrier/staging sequence identical to R5.
    for (int kt2 = 0; kt2 < 8; ++kt2) {
        __syncthreads();                 // buf0 (tile 2k) staged; buf1 free
        STAGE(2 * kt2 + 1, 1);           // prefetch odd tile
        LOADC(cB, 2 * kt2 + 1);          // c for odd tile (consumed after next barrier)
        DOTILE(0, cA);                   // compute even tile
        __syncthreads();                 // buf1 staged; buf0 free
        if (kt2 < 7) {
            STAGE(2 * kt2 + 2, 0);       // prefetch next even tile
            LOADC(cA, 2 * kt2 + 2);      // c for next even tile
        }
        DOTILE(1, cB);                   // compute odd tile
    }

    // epilogue: normalize and write bf16 (B,N,H,D)
    float l = l_lane;
    l += __shfl_xor(l, 16);
    l += __shfl_xor(l, 32);
    const float inv = 1.f / l;
    const int qrow = qt * 128 + w * 16 + l15;
    const size_t ob = ((size_t)(b * NN + qrow) * HH + h) * DD;
#pragma unroll
    for (int db = 0; db < 4; ++db) {
        uint2 pk;
        pk.x = pk2(oT[db][0] * inv, oT[db][1] * inv);
        pk.y = pk2(oT[db][2] * inv, oT[db][3] * inv);
        *(uint2*)&att[ob + db * 16 + quad * 4] = pk;
    }
}

// ---------------------------------------------------------------- out GEMM
// out fp32 = att·Wo^T + bo. 128x64 tile -> 512 blocks = 2/CU. (original)
__global__ __launch_bounds__(256) void gemm_out(const unsigned short* __restrict__ A,
                                                const unsigned short* __restrict__ B,
                                                float* __restrict__ out,
                                                const float* __restrict__ bias) {
    constexpr int K = CC;
    __shared__ unsigned short As[128 * 32];
    __shared__ unsigned short Bs[64 * 32];
    const int t = threadIdx.x;
    const int w = t >> 6, lane = t & 63, l15 = lane & 15, quad = lane >> 4;
    const int m0 = blockIdx.x * 128, n0 = blockIdx.y * 64;
    const int wm = (w >> 1) * 64, wn = (w & 1) * 32;

    f32x4 acc[4][2];
#pragma unroll
    for (int i = 0; i < 4; ++i)
#pragma unroll
        for (int j = 0; j < 2; ++j)
#pragma unroll
            for (int r = 0; r < 4; ++r) acc[i][j][r] = 0.f;

    for (int kb = 0; kb < K; kb += 32) {
        __syncthreads();
#pragma unroll
        for (int j = 0; j < 2; ++j) {
            int id = j * 256 + t;
            int row = id >> 2, c4 = (id & 3) * 8;
            gload_lds16(&A[(size_t)(m0 + row) * K + kb + c4], &As[id * 8]);
        }
        {
            int row = t >> 2, c4 = (t & 3) * 8;
            gload_lds16(&B[(size_t)(n0 + row) * K + kb + c4], &Bs[t * 8]);
        }
        __syncthreads();
        bf16x8 af[4], bfr[2];
#pragma unroll
        for (int i = 0; i < 4; ++i)
            af[i] = *(const bf16x8*)&As[(wm + i * 16 + l15) * 32 + quad * 8];
#pragma unroll
        for (int j = 0; j < 2; ++j)
            bfr[j] = *(const bf16x8*)&Bs[(wn + j * 16 + l15) * 32 + quad * 8];
#pragma unroll
        for (int i = 0; i < 4; ++i)
#pragma unroll
            for (int j = 0; j < 2; ++j)
                acc[i][j] = __builtin_amdgcn_mfma_f32_16x16x32_bf16(af[i], bfr[j], acc[i][j], 0, 0, 0);
    }

#pragma unroll
    for (int i = 0; i < 4; ++i)
#pragma unroll
        for (int j = 0; j < 2; ++j) {
            const int col = n0 + wn + j * 16 + l15;
            const int row_base = m0 + wm + i * 16 + quad * 4;
            const float bc = bias[col];
#pragma unroll
            for (int r = 0; r < 4; ++r)
                out[(size_t)(row_base + r) * CC + col] = acc[i][j][r] + bc;
        }
}

// ---------------------------------------------------------------- launch
extern "C" void kernel_launch(void* const* d_in, const int* in_sizes, int n_in,
                              void* d_out, int out_size, void* d_ws, size_t ws_size,
                              hipStream_t stream) {
    const float* hs   = (const float*)d_in[0];
    const float* pos  = (const float*)d_in[1];
    const float* Wq   = (const float*)d_in[2];
    const float* bq   = (const float*)d_in[3];
    const float* Wk   = (const float*)d_in[4];
    const float* bk   = (const float*)d_in[5];
    const float* Wv   = (const float*)d_in[6];
    const float* bv   = (const float*)d_in[7];
    const float* Wpos = (const float*)d_in[8];
    const float* pbu  = (const float*)d_in[9];
    const float* pbv  = (const float*)d_in[10];
    const float* Wo   = (const float*)d_in[11];
    const float* bo   = (const float*)d_in[12];
    float* out = (float*)d_out;

    const size_t nHS = (size_t)MM * CC;
    const size_t nW  = (size_t)CC * CC;

    unsigned short* p = (unsigned short*)d_ws;
    unsigned short* hsb  = p;            p += nHS;
    unsigned short* posb = p;            p += nHS;
    unsigned short* wqb  = p;            p += nW;
    unsigned short* wkb  = p;            p += nW;
    unsigned short* wvb  = p;            p += nW;
    unsigned short* wpb  = p;            p += nW;
    unsigned short* wob  = p;            p += nW;
    unsigned short* qsb  = p;            p += nHS;
    unsigned short* kbf  = p;            p += nHS;
    unsigned short* pbf  = p;            p += nHS;
    unsigned short* kpb  = p;            p += nHS;
    unsigned short* vtb  = p;            p += nHS;
    float* cb = (float*)p;               p += (size_t)BB * HH * NN * 2;
    unsigned short* attb = hsb;          // alias: hsb dead after gemm_qkvp

    CastArgs ca;
    ca.src[0] = hs;   ca.dst[0] = hsb;  ca.n4[0] = (int)(nHS / 4);
    ca.src[1] = pos;  ca.dst[1] = posb; ca.n4[1] = (int)(nHS / 4);
    ca.src[2] = Wq;   ca.dst[2] = wqb;  ca.n4[2] = (int)(nW / 4);
    ca.src[3] = Wk;   ca.dst[3] = wkb;  ca.n4[3] = (int)(nW / 4);
    ca.src[4] = Wv;   ca.dst[4] = wvb;  ca.n4[4] = (int)(nW / 4);
    ca.src[5] = Wpos; ca.dst[5] = wpb;  ca.n4[5] = (int)(nW / 4);
    ca.src[6] = Wo;   ca.dst[6] = wob;  ca.n4[6] = (int)(nW / 4);
    dim3 cgrid((unsigned)(nHS / 4 / 256), 7);
    cast_all<<<cgrid, 256, 0, stream>>>(ca);

    GemmBatch gb;
    gb.A[0] = hsb;  gb.B[0] = wqb; gb.out[0] = qsb; gb.bias[0] = bq;
    gb.A[1] = hsb;  gb.B[1] = wkb; gb.out[1] = kbf; gb.bias[1] = bk;
    gb.A[2] = hsb;  gb.B[2] = wvb; gb.out[2] = vtb; gb.bias[2] = bv;
    gb.A[3] = posb; gb.B[3] = wpb; gb.out[3] = pbf; gb.bias[3] = nullptr;
    dim3 ggrid(MM / 128, CC / 128, 4);
    gemm_qkvp<<<ggrid, 256, 0, stream>>>(gb);

    fuse_kpc<<<MM * HH / 4, 256, 0, stream>>>(kbf, pbf, pbu, pbv, kpb, cb);

    dim3 agrid(NN / 128, HH, BB);
    attn_kernel<<<agrid, 512, 0, stream>>>(qsb, kpb, vtb, cb, attb);

    dim3 ogrid(MM / 128, CC / 64);
    gemm_out<<<ogrid, 256, 0, stream>>>(attb, wob, out, bo);
}

// Round 10
// 256.020 us; speedup vs baseline: 1.1111x; 1.0734x over previous
//
#include <hip/hip_runtime.h>
#include <hip/hip_bf16.h>

// WhaleAttention: B=2, N=2048, C=1024, H=16, D=64, SCALE=1/8
// R9: R8's c-pipelining regressed attn 76.5->91.5 (VGPR 52->92, occ 34->21):
// 64 f32 of cross-barrier c-state cost more than the latency it hid. Full
// revert to R5 (best measured, 257.45us). ONE isolated change: fuse_kpc
// vectorized bf16x8 (was scalar 2B/lane loads — Common-mistake #2; m146:
// 2.08x on same pattern). Each lane: 8 els, per-head dot via 3 shfl_xor.

typedef short bf16x8 __attribute__((ext_vector_type(8)));
typedef float f32x4 __attribute__((ext_vector_type(4)));

#define BB 2
#define NN 2048
#define CC 1024
#define HH 16
#define DD 64
#define MM (BB * NN)      // 4096 rows
#define SC2E 0.18033688f  // SCALE * log2(e)

__device__ __forceinline__ unsigned short f2bf(float f) {
    union { float f; unsigned int u; } x; x.f = f;
    unsigned int r = x.u + 0x7FFFu + ((x.u >> 16) & 1u);
    return (unsigned short)(r >> 16);
}

__device__ __forceinline__ float bf2f(unsigned short s) {
    union { unsigned int u; float f; } x; x.u = ((unsigned int)s) << 16;
    return x.f;
}

__device__ __forceinline__ unsigned int pk2(float a, float b) {
    __hip_bfloat162 h = __float22bfloat162_rn(make_float2(a, b));
    unsigned int u; __builtin_memcpy(&u, &h, 4); return u;
}

typedef __attribute__((address_space(1))) const unsigned int* gas1_t;
typedef __attribute__((address_space(3))) unsigned int* las3_t;

__device__ __forceinline__ void gload_lds16(const unsigned short* g, unsigned short* l) {
    __builtin_amdgcn_global_load_lds((gas1_t)g, (las3_t)l, 16, 0, 0);
}

// ---------------------------------------------------------------- cast kernel
struct CastArgs {
    const float* src[7];
    unsigned short* dst[7];
    int n4[7];
};
__global__ __launch_bounds__(256) void cast_all(CastArgs a) {
    const int seg = blockIdx.y;
    const int i = blockIdx.x * 256 + threadIdx.x;
    if (i >= a.n4[seg]) return;
    float4 v = ((const float4*)a.src[seg])[i];
    uint2 u;
    u.x = pk2(v.x, v.y);
    u.y = pk2(v.z, v.w);
    ((uint2*)a.dst[seg])[i] = u;
}

// ---------------------------------------------------------------- batched GEMM
// z=0: q (bf16, (acc+bq)*SC2E), z=1: k (+bk), z=2: v transposed (B,H,D,N)
// via LDS transpose epilogue, z=3: p (plain). 128x128 tile.
// BK=64 (16 K-iters, 2 barriers each). LDS = two [128][32] slabs per
// operand (m97 bank pattern preserved).
struct GemmBatch {
    const unsigned short* A[4];
    const unsigned short* B[4];
    unsigned short* out[4];
    const float* bias[4];
};
__global__ __launch_bounds__(256) void gemm_qkvp(GemmBatch g) {
    constexpr int K = CC;
    __shared__ unsigned short Sh[2 * 128 * 64];   // As(2 slabs) | Bs(2 slabs); Tr reuse
    unsigned short* As = Sh;              // [kk][row][32]: slab kk at kk*4096
    unsigned short* Bs = Sh + 128 * 64;
    const int z = blockIdx.z;
    const unsigned short* __restrict__ A = g.A[z];
    const unsigned short* __restrict__ B = g.B[z];
    unsigned short* __restrict__ out = g.out[z];
    const float* __restrict__ bias = g.bias[z];

    const int t = threadIdx.x;
    const int w = t >> 6, lane = t & 63, l15 = lane & 15, quad = lane >> 4;
    const int m0 = blockIdx.x * 128, n0 = blockIdx.y * 128;
    const int wm = (w >> 1) * 64, wn = (w & 1) * 64;

    f32x4 acc[4][4];
#pragma unroll
    for (int i = 0; i < 4; ++i)
#pragma unroll
        for (int j = 0; j < 4; ++j)
#pragma unroll
            for (int r = 0; r < 4; ++r) acc[i][j][r] = 0.f;

    for (int kb = 0; kb < K; kb += 64) {
        __syncthreads();
        // stage 128x64 per operand as two [128][32] slabs.
        // 1024 chunks of 16B per operand; 256 threads x 4.
#pragma unroll
        for (int j = 0; j < 4; ++j) {
            const int id = j * 256 + t;           // 0..1023
            const int half = id >> 9;             // col-slab 0/1
            const int id9 = id & 511;             // within-slab chunk
            const int row = id9 >> 2, c4 = (id9 & 3) * 8;
            gload_lds16(&A[(size_t)(m0 + row) * K + kb + half * 32 + c4],
                        &As[half * 4096 + id9 * 8]);
            gload_lds16(&B[(size_t)(n0 + row) * K + kb + half * 32 + c4],
                        &Bs[half * 4096 + id9 * 8]);
        }
        __syncthreads();
#pragma unroll
        for (int kk = 0; kk < 2; ++kk) {
            bf16x8 af[4], bfr[4];
#pragma unroll
            for (int i = 0; i < 4; ++i)
                af[i] = *(const bf16x8*)&As[kk * 4096 + (wm + i * 16 + l15) * 32 + quad * 8];
#pragma unroll
            for (int j = 0; j < 4; ++j)
                bfr[j] = *(const bf16x8*)&Bs[kk * 4096 + (wn + j * 16 + l15) * 32 + quad * 8];
#pragma unroll
            for (int i = 0; i < 4; ++i)
#pragma unroll
                for (int j = 0; j < 4; ++j)
                    acc[i][j] = __builtin_amdgcn_mfma_f32_16x16x32_bf16(af[i], bfr[j], acc[i][j], 0, 0, 0);
        }
    }

    if (z != 2) {
        const float sc = (z == 0) ? SC2E : 1.f;
#pragma unroll
        for (int i = 0; i < 4; ++i)
#pragma unroll
            for (int j = 0; j < 4; ++j) {
                const int col = n0 + wn + j * 16 + l15;
                const int row_base = m0 + wm + i * 16 + quad * 4;
                const float bc = bias ? bias[col] : 0.f;
#pragma unroll
                for (int r = 0; r < 4; ++r)
                    out[(size_t)(row_base + r) * CC + col] = f2bf((acc[i][j][r] + bc) * sc);
            }
    } else {
        // v^T epilogue: per-wave 16-col chunks through LDS (reusing Sh;
        // per-wave 16x72 = 2304B, 4 waves = 9.2KB), then 128B-contiguous
        // dwordx4 stores to vt (B,H,D,N).
        __syncthreads();    // all waves done reading As/Bs fragments
        unsigned short* Tr = &Sh[w * 1152];   // 16 cols x stride 72
        const int bI = (m0 + wm) >> 11, nseq0 = (m0 + wm) & 2047;
        const int colL = lane >> 3;           // 0..7
        const int mL = (lane & 7) * 8;        // 0..56
#pragma unroll
        for (int j = 0; j < 4; ++j) {
            const int col = n0 + wn + j * 16 + l15;
            const float bc = bias[col];
#pragma unroll
            for (int i = 0; i < 4; ++i) {
                uint2 pk;
                pk.x = pk2(acc[i][j][0] + bc, acc[i][j][1] + bc);
                pk.y = pk2(acc[i][j][2] + bc, acc[i][j][3] + bc);
                *(uint2*)&Tr[l15 * 72 + i * 16 + quad * 4] = pk;
            }
            // same-wave DS ops are in-order; reads below see the writes above
#pragma unroll
            for (int p = 0; p < 2; ++p) {
                const int cl = p * 8 + colL;
                uint4 vv = *(const uint4*)&Tr[cl * 72 + mL];
                const int gcol = n0 + wn + j * 16 + cl;
                const int hh = gcol >> 6, dd = gcol & 63;
                *(uint4*)&out[((size_t)(bI * 16 + hh) * 64 + dd) * 2048 + nseq0 + mL] = vv;
            }
        }
    }
}

// ---------------------------------------------------------------- fuse kp + c
// R9: vectorized. Block = 256 threads = 4 waves; waves (w>>1) pick the row,
// (w&1) picks the half-row. Lane handles 8 contiguous bf16 (16B loads).
// head h = (w&1)*8 + (lane>>3); d-range (lane&7)*8..+7; dot reduced over the
// 8-lane group via shfl_xor 1/2/4; lane (l&7)==0 writes c.
__global__ __launch_bounds__(256) void fuse_kpc(const unsigned short* __restrict__ k,
                                                const unsigned short* __restrict__ pp,
                                                const float* __restrict__ pbu,
                                                const float* __restrict__ pbv,
                                                unsigned short* __restrict__ kp,
                                                float* __restrict__ c) {
    const int t = threadIdx.x;
    const int w = t >> 6, lane = t & 63;
    const int row = blockIdx.x * 2 + (w >> 1);         // row = b*N + n
    const int col0 = (w & 1) * 512 + lane * 8;         // 8 els per lane
    const size_t off = (size_t)row * CC + col0;
    const int h = col0 >> 6;                           // head of this 8-chunk
    const int d0 = col0 & 63;                          // d-offset within head

    bf16x8 kv8 = *(const bf16x8*)&k[off];
    bf16x8 pv8 = *(const bf16x8*)&pp[off];
    bf16x8 s8;
    float val = 0.f;
#pragma unroll
    for (int j = 0; j < 8; ++j) {
        const float kv = bf2f((unsigned short)kv8[j]);
        const float pv = bf2f((unsigned short)pv8[j]);
        s8[j] = (short)f2bf(kv + pv);
        val += pbu[h * 64 + d0 + j] * kv + pbv[h * 64 + d0 + j] * pv;
    }
    *(bf16x8*)&kp[off] = s8;
#pragma unroll
    for (int o = 1; o < 8; o <<= 1) val += __shfl_xor(val, o);
    if ((lane & 7) == 0) {
        const int b = row >> 11, n = row & 2047;
        c[((size_t)(b * HH + h)) * NN + n] = val * SC2E;
    }
}

// ---------------------------------------------------------------- attention
// R2-best shape (76.5us measured): (qt,h,b) -> 128 q rows, 8 waves x 16 q.
// KVBLK=128, double-buffered K/V staging, prefetch after the single per-iter
// barrier. Per tile: two 64-key halves through {QK^T (c-init), exp2, Ps
// roundtrip, PV} reusing s regs / Ps buffer. setprio(1) around MFMA.
__global__ __launch_bounds__(512) void attn_kernel(const unsigned short* __restrict__ q,
                                                   const unsigned short* __restrict__ kp,
                                                   const unsigned short* __restrict__ vt,
                                                   const float* __restrict__ cb,
                                                   unsigned short* __restrict__ att) {
    __shared__ unsigned short Ks[2][128 * 64];   // [key][d], XOR-swizzled
    __shared__ unsigned short Vs[2][64 * 128];   // [d][key], XOR-swizzled
    __shared__ unsigned short Ps[8][16 * 64];    // per-wave P round-trip

    const int t = threadIdx.x;
    const int w = t >> 6, lane = t & 63, l15 = lane & 15, quad = lane >> 4;
    const int qt = blockIdx.x, h = blockIdx.y, b = blockIdx.z;
    const int e3 = l15 & 7;

    // Q fragment: 16 q rows per wave (registers, loaded once)
    bf16x8 qf[2];
    {
        const int qrow = qt * 128 + w * 16 + l15;
        const size_t qoff = ((size_t)(b * NN + qrow) * HH + h) * DD;
#pragma unroll
        for (int c2 = 0; c2 < 2; ++c2)
            qf[c2] = *(const bf16x8*)&q[qoff + c2 * 32 + quad * 8];
    }

    f32x4 oT[4];
    float l_lane = 0.f;
#pragma unroll
    for (int db = 0; db < 4; ++db)
#pragma unroll
        for (int r = 0; r < 4; ++r) oT[db][r] = 0.f;

    const size_t kbase = (size_t)b * NN * CC + (size_t)h * DD;
    const size_t vbase = (size_t)(b * HH + h) * DD * NN;
    const size_t cbase = (size_t)(b * HH + h) * NN;

    // staging maps (kt-invariant): 512 threads x 2 segments, 16B each.
    // K tile: 128 rows x 8 chunks; V tile: 64 d-rows x 16 chunks. XOR
    // pre-swizzle on the GLOBAL chunk (involution; LDS dest stays linear).
    int krow[2], kgc[2], vd[2], vgc[2];
#pragma unroll
    for (int j = 0; j < 2; ++j) {
        const int id = j * 512 + t;
        krow[j] = id >> 3;
        kgc[j] = ((id & 7) ^ (krow[j] & 7)) * 8;
        vd[j] = id >> 4;
        vgc[j] = ((id & 15) ^ (vd[j] & 7)) * 8;
    }

    // prologue: stage kt=0 into buffer 0
#pragma unroll
    for (int j = 0; j < 2; ++j) {
        const int id = j * 512 + t;
        gload_lds16(&kp[kbase + (size_t)krow[j] * CC + kgc[j]], &Ks[0][id * 8]);
        gload_lds16(&vt[vbase + (size_t)vd[j] * NN + vgc[j]], &Vs[0][id * 8]);
    }

    for (int kt = 0; kt < NN / 128; ++kt) {
        const int cur = kt & 1;
        __syncthreads();   // drains prefetch issued last iter (full iter of cover)
        if (kt + 1 < NN / 128) {
#pragma unroll
            for (int j = 0; j < 2; ++j) {
                const int id = j * 512 + t;
                gload_lds16(&kp[kbase + (size_t)((kt + 1) * 128 + krow[j]) * CC + kgc[j]],
                            &Ks[cur ^ 1][id * 8]);
                gload_lds16(&vt[vbase + (size_t)vd[j] * NN + (kt + 1) * 128 + vgc[j]],
                            &Vs[cur ^ 1][id * 8]);
            }
        }

        // c-init for the whole 128-key tile (L2-hot; batched so latency
        // overlaps the first half's ds_reads)
        f32x4 c8r[8];
#pragma unroll
        for (int t8 = 0; t8 < 8; ++t8)
            c8r[t8] = *(const f32x4*)&cb[cbase + kt * 128 + t8 * 16 + quad * 4];

#pragma unroll
        for (int half = 0; half < 2; ++half) {
            // S^T (64 keys x 16 q per wave), c-initialized
            f32x4 s[4];
#pragma unroll
            for (int t4 = 0; t4 < 4; ++t4) s[t4] = c8r[half * 4 + t4];

            __builtin_amdgcn_s_setprio(1);
#pragma unroll
            for (int t4 = 0; t4 < 4; ++t4) {
                const int row = half * 64 + t4 * 16 + l15;
#pragma unroll
                for (int c2 = 0; c2 < 2; ++c2) {
                    bf16x8 kf = *(const bf16x8*)&Ks[cur][row * 64 + (((c2 * 4 + quad) ^ e3) * 8)];
                    s[t4] = __builtin_amdgcn_mfma_f32_16x16x32_bf16(kf, qf[c2], s[t4], 0, 0, 0);
                }
            }
            __builtin_amdgcn_s_setprio(0);

            // fixed-base exp2 softmax; l reduced once at the end
            float rs = 0.f;
#pragma unroll
            for (int t4 = 0; t4 < 4; ++t4)
#pragma unroll
                for (int r = 0; r < 4; ++r) {
                    float pv = exp2f(s[t4][r]);
                    s[t4][r] = pv;
                    rs += pv;
                }
            l_lane += rs;
            // Ps store: XOR-swizzle whole 8-short blocks by (l15&7), no pad.
#pragma unroll
            for (int t4 = 0; t4 < 4; ++t4) {
                uint2 pk;
                pk.x = pk2(s[t4][0], s[t4][1]);
                pk.y = pk2(s[t4][2], s[t4][3]);
                const int blk = t4 * 2 + (quad >> 1);
                *(uint2*)&Ps[w][l15 * 64 + ((blk ^ e3) * 8) + (quad & 1) * 4] = pk;
            }
            // no barrier: Ps[w] wave-private; same-wave DS ops in-order

            // O^T += V^T · P  (keys half*64 .. half*64+63)
            __builtin_amdgcn_s_setprio(1);
#pragma unroll
            for (int c2 = 0; c2 < 2; ++c2) {
                bf16x8 pf = *(const bf16x8*)&Ps[w][l15 * 64 + (((c2 * 4 + quad) ^ e3) * 8)];
#pragma unroll
                for (int db = 0; db < 4; ++db) {
                    bf16x8 vf = *(const bf16x8*)&Vs[cur][(db * 16 + l15) * 128 +
                                                         (((half * 8 + c2 * 4 + quad) ^ e3) * 8)];
                    oT[db] = __builtin_amdgcn_mfma_f32_16x16x32_bf16(vf, pf, oT[db], 0, 0, 0);
                }
            }
            __builtin_amdgcn_s_setprio(0);
        }
    }

    // epilogue: normalize and write bf16 (B,N,H,D)
    float l = l_lane;
    l += __shfl_xor(l, 16);
    l += __shfl_xor(l, 32);
    const float inv = 1.f / l;
    const int qrow = qt * 128 + w * 16 + l15;
    const size_t ob = ((size_t)(b * NN + qrow) * HH + h) * DD;
#pragma unroll
    for (int db = 0; db < 4; ++db) {
        uint2 pk;
        pk.x = pk2(oT[db][0] * inv, oT[db][1] * inv);
        pk.y = pk2(oT[db][2] * inv, oT[db][3] * inv);
        *(uint2*)&att[ob + db * 16 + quad * 4] = pk;
    }
}

// ---------------------------------------------------------------- out GEMM
// out fp32 = att·Wo^T + bo. 128x64 tile -> 512 blocks = 2/CU. (original)
__global__ __launch_bounds__(256) void gemm_out(const unsigned short* __restrict__ A,
                                                const unsigned short* __restrict__ B,
                                                float* __restrict__ out,
                                                const float* __restrict__ bias) {
    constexpr int K = CC;
    __shared__ unsigned short As[128 * 32];
    __shared__ unsigned short Bs[64 * 32];
    const int t = threadIdx.x;
    const int w = t >> 6, lane = t & 63, l15 = lane & 15, quad = lane >> 4;
    const int m0 = blockIdx.x * 128, n0 = blockIdx.y * 64;
    const int wm = (w >> 1) * 64, wn = (w & 1) * 32;

    f32x4 acc[4][2];
#pragma unroll
    for (int i = 0; i < 4; ++i)
#pragma unroll
        for (int j = 0; j < 2; ++j)
#pragma unroll
            for (int r = 0; r < 4; ++r) acc[i][j][r] = 0.f;

    for (int kb = 0; kb < K; kb += 32) {
        __syncthreads();
#pragma unroll
        for (int j = 0; j < 2; ++j) {
            int id = j * 256 + t;
            int row = id >> 2, c4 = (id & 3) * 8;
            gload_lds16(&A[(size_t)(m0 + row) * K + kb + c4], &As[id * 8]);
        }
        {
            int row = t >> 2, c4 = (t & 3) * 8;
            gload_lds16(&B[(size_t)(n0 + row) * K + kb + c4], &Bs[t * 8]);
        }
        __syncthreads();
        bf16x8 af[4], bfr[2];
#pragma unroll
        for (int i = 0; i < 4; ++i)
            af[i] = *(const bf16x8*)&As[(wm + i * 16 + l15) * 32 + quad * 8];
#pragma unroll
        for (int j = 0; j < 2; ++j)
            bfr[j] = *(const bf16x8*)&Bs[(wn + j * 16 + l15) * 32 + quad * 8];
#pragma unroll
        for (int i = 0; i < 4; ++i)
#pragma unroll
            for (int j = 0; j < 2; ++j)
                acc[i][j] = __builtin_amdgcn_mfma_f32_16x16x32_bf16(af[i], bfr[j], acc[i][j], 0, 0, 0);
    }

#pragma unroll
    for (int i = 0; i < 4; ++i)
#pragma unroll
        for (int j = 0; j < 2; ++j) {
            const int col = n0 + wn + j * 16 + l15;
            const int row_base = m0 + wm + i * 16 + quad * 4;
            const float bc = bias[col];
#pragma unroll
            for (int r = 0; r < 4; ++r)
                out[(size_t)(row_base + r) * CC + col] = acc[i][j][r] + bc;
        }
}

// ---------------------------------------------------------------- launch
extern "C" void kernel_launch(void* const* d_in, const int* in_sizes, int n_in,
                              void* d_out, int out_size, void* d_ws, size_t ws_size,
                              hipStream_t stream) {
    const float* hs   = (const float*)d_in[0];
    const float* pos  = (const float*)d_in[1];
    const float* Wq   = (const float*)d_in[2];
    const float* bq   = (const float*)d_in[3];
    const float* Wk   = (const float*)d_in[4];
    const float* bk   = (const float*)d_in[5];
    const float* Wv   = (const float*)d_in[6];
    const float* bv   = (const float*)d_in[7];
    const float* Wpos = (const float*)d_in[8];
    const float* pbu  = (const float*)d_in[9];
    const float* pbv  = (const float*)d_in[10];
    const float* Wo   = (const float*)d_in[11];
    const float* bo   = (const float*)d_in[12];
    float* out = (float*)d_out;

    const size_t nHS = (size_t)MM * CC;
    const size_t nW  = (size_t)CC * CC;

    unsigned short* p = (unsigned short*)d_ws;
    unsigned short* hsb  = p;            p += nHS;
    unsigned short* posb = p;            p += nHS;
    unsigned short* wqb  = p;            p += nW;
    unsigned short* wkb  = p;            p += nW;
    unsigned short* wvb  = p;            p += nW;
    unsigned short* wpb  = p;            p += nW;
    unsigned short* wob  = p;            p += nW;
    unsigned short* qsb  = p;            p += nHS;
    unsigned short* kbf  = p;            p += nHS;
    unsigned short* pbf  = p;            p += nHS;
    unsigned short* kpb  = p;            p += nHS;
    unsigned short* vtb  = p;            p += nHS;
    float* cb = (float*)p;               p += (size_t)BB * HH * NN * 2;
    unsigned short* attb = hsb;          // alias: hsb dead after gemm_qkvp

    CastArgs ca;
    ca.src[0] = hs;   ca.dst[0] = hsb;  ca.n4[0] = (int)(nHS / 4);
    ca.src[1] = pos;  ca.dst[1] = posb; ca.n4[1] = (int)(nHS / 4);
    ca.src[2] = Wq;   ca.dst[2] = wqb;  ca.n4[2] = (int)(nW / 4);
    ca.src[3] = Wk;   ca.dst[3] = wkb;  ca.n4[3] = (int)(nW / 4);
    ca.src[4] = Wv;   ca.dst[4] = wvb;  ca.n4[4] = (int)(nW / 4);
    ca.src[5] = Wpos; ca.dst[5] = wpb;  ca.n4[5] = (int)(nW / 4);
    ca.src[6] = Wo;   ca.dst[6] = wob;  ca.n4[6] = (int)(nW / 4);
    dim3 cgrid((unsigned)(nHS / 4 / 256), 7);
    cast_all<<<cgrid, 256, 0, stream>>>(ca);

    GemmBatch gb;
    gb.A[0] = hsb;  gb.B[0] = wqb; gb.out[0] = qsb; gb.bias[0] = bq;
    gb.A[1] = hsb;  gb.B[1] = wkb; gb.out[1] = kbf; gb.bias[1] = bk;
    gb.A[2] = hsb;  gb.B[2] = wvb; gb.out[2] = vtb; gb.bias[2] = bv;
    gb.A[3] = posb; gb.B[3] = wpb; gb.out[3] = pbf; gb.bias[3] = nullptr;
    dim3 ggrid(MM / 128, CC / 128, 4);
    gemm_qkvp<<<ggrid, 256, 0, stream>>>(gb);

    fuse_kpc<<<MM / 2, 256, 0, stream>>>(kbf, pbf, pbu, pbv, kpb, cb);

    dim3 agrid(NN / 128, HH, BB);
    attn_kernel<<<agrid, 512, 0, stream>>>(qsb, kpb, vtb, cb, attb);

    dim3 ogrid(MM / 128, CC / 64);
    gemm_out<<<ogrid, 256, 0, stream>>>(attb, wob, out, bo);
}

// Round 11
// 251.598 us; speedup vs baseline: 1.1306x; 1.0176x over previous
//
#include <hip/hip_runtime.h>
#include <hip/hip_bf16.h>

// WhaleAttention: B=2, N=2048, C=1024, H=16, D=64, SCALE=1/8
// R10: R9 base (session best, 256.0us) + two audited, independent micro-fixes:
//  (1) cast_all exact 1D grid: 13312 blocks (was 28672 with 15360 empty).
//  (2) gemm_out BK 32->64 (two [*][32] slabs, m97 bank pattern) — mirrors
//      R5's measured-safe qkvp change; halves barrier count, 24KB LDS.
// attn / gemm_qkvp / fuse_kpc byte-identical to R9.

typedef short bf16x8 __attribute__((ext_vector_type(8)));
typedef float f32x4 __attribute__((ext_vector_type(4)));

#define BB 2
#define NN 2048
#define CC 1024
#define HH 16
#define DD 64
#define MM (BB * NN)      // 4096 rows
#define SC2E 0.18033688f  // SCALE * log2(e)

__device__ __forceinline__ unsigned short f2bf(float f) {
    union { float f; unsigned int u; } x; x.f = f;
    unsigned int r = x.u + 0x7FFFu + ((x.u >> 16) & 1u);
    return (unsigned short)(r >> 16);
}

__device__ __forceinline__ float bf2f(unsigned short s) {
    union { unsigned int u; float f; } x; x.u = ((unsigned int)s) << 16;
    return x.f;
}

__device__ __forceinline__ unsigned int pk2(float a, float b) {
    __hip_bfloat162 h = __float22bfloat162_rn(make_float2(a, b));
    unsigned int u; __builtin_memcpy(&u, &h, 4); return u;
}

typedef __attribute__((address_space(1))) const unsigned int* gas1_t;
typedef __attribute__((address_space(3))) unsigned int* las3_t;

__device__ __forceinline__ void gload_lds16(const unsigned short* g, unsigned short* l) {
    __builtin_amdgcn_global_load_lds((gas1_t)g, (las3_t)l, 16, 0, 0);
}

// ---------------------------------------------------------------- cast kernel
// R10: exact 1D grid. Blocks [0,4096) hs, [4096,8192) pos, then 5x1024 for
// Wq, Wk, Wv, Wpos, Wo. Every block fully active (no early-exit waste).
struct CastArgs {
    const float* src[7];
    unsigned short* dst[7];
};
__global__ __launch_bounds__(256) void cast_all(CastArgs a) {
    const int b = blockIdx.x;
    int seg, i;
    if (b < 8192) {
        seg = b >> 12;                       // 0 or 1
        i = (b & 4095) * 256 + threadIdx.x;
    } else {
        const int b2 = b - 8192;
        seg = 2 + (b2 >> 10);                // 2..6
        i = (b2 & 1023) * 256 + threadIdx.x;
    }
    float4 v = ((const float4*)a.src[seg])[i];
    uint2 u;
    u.x = pk2(v.x, v.y);
    u.y = pk2(v.z, v.w);
    ((uint2*)a.dst[seg])[i] = u;
}

// ---------------------------------------------------------------- batched GEMM
// z=0: q (bf16, (acc+bq)*SC2E), z=1: k (+bk), z=2: v transposed (B,H,D,N)
// via LDS transpose epilogue, z=3: p (plain). 128x128 tile.
// BK=64 (16 K-iters, 2 barriers each). LDS = two [128][32] slabs per
// operand (m97 bank pattern preserved).
struct GemmBatch {
    const unsigned short* A[4];
    const unsigned short* B[4];
    unsigned short* out[4];
    const float* bias[4];
};
__global__ __launch_bounds__(256) void gemm_qkvp(GemmBatch g) {
    constexpr int K = CC;
    __shared__ unsigned short Sh[2 * 128 * 64];   // As(2 slabs) | Bs(2 slabs); Tr reuse
    unsigned short* As = Sh;              // [kk][row][32]: slab kk at kk*4096
    unsigned short* Bs = Sh + 128 * 64;
    const int z = blockIdx.z;
    const unsigned short* __restrict__ A = g.A[z];
    const unsigned short* __restrict__ B = g.B[z];
    unsigned short* __restrict__ out = g.out[z];
    const float* __restrict__ bias = g.bias[z];

    const int t = threadIdx.x;
    const int w = t >> 6, lane = t & 63, l15 = lane & 15, quad = lane >> 4;
    const int m0 = blockIdx.x * 128, n0 = blockIdx.y * 128;
    const int wm = (w >> 1) * 64, wn = (w & 1) * 64;

    f32x4 acc[4][4];
#pragma unroll
    for (int i = 0; i < 4; ++i)
#pragma unroll
        for (int j = 0; j < 4; ++j)
#pragma unroll
            for (int r = 0; r < 4; ++r) acc[i][j][r] = 0.f;

    for (int kb = 0; kb < K; kb += 64) {
        __syncthreads();
        // stage 128x64 per operand as two [128][32] slabs.
        // 1024 chunks of 16B per operand; 256 threads x 4.
#pragma unroll
        for (int j = 0; j < 4; ++j) {
            const int id = j * 256 + t;           // 0..1023
            const int half = id >> 9;             // col-slab 0/1
            const int id9 = id & 511;             // within-slab chunk
            const int row = id9 >> 2, c4 = (id9 & 3) * 8;
            gload_lds16(&A[(size_t)(m0 + row) * K + kb + half * 32 + c4],
                        &As[half * 4096 + id9 * 8]);
            gload_lds16(&B[(size_t)(n0 + row) * K + kb + half * 32 + c4],
                        &Bs[half * 4096 + id9 * 8]);
        }
        __syncthreads();
#pragma unroll
        for (int kk = 0; kk < 2; ++kk) {
            bf16x8 af[4], bfr[4];
#pragma unroll
            for (int i = 0; i < 4; ++i)
                af[i] = *(const bf16x8*)&As[kk * 4096 + (wm + i * 16 + l15) * 32 + quad * 8];
#pragma unroll
            for (int j = 0; j < 4; ++j)
                bfr[j] = *(const bf16x8*)&Bs[kk * 4096 + (wn + j * 16 + l15) * 32 + quad * 8];
#pragma unroll
            for (int i = 0; i < 4; ++i)
#pragma unroll
                for (int j = 0; j < 4; ++j)
                    acc[i][j] = __builtin_amdgcn_mfma_f32_16x16x32_bf16(af[i], bfr[j], acc[i][j], 0, 0, 0);
        }
    }

    if (z != 2) {
        const float sc = (z == 0) ? SC2E : 1.f;
#pragma unroll
        for (int i = 0; i < 4; ++i)
#pragma unroll
            for (int j = 0; j < 4; ++j) {
                const int col = n0 + wn + j * 16 + l15;
                const int row_base = m0 + wm + i * 16 + quad * 4;
                const float bc = bias ? bias[col] : 0.f;
#pragma unroll
                for (int r = 0; r < 4; ++r)
                    out[(size_t)(row_base + r) * CC + col] = f2bf((acc[i][j][r] + bc) * sc);
            }
    } else {
        // v^T epilogue: per-wave 16-col chunks through LDS (reusing Sh;
        // per-wave 16x72 = 2304B, 4 waves = 9.2KB), then 128B-contiguous
        // dwordx4 stores to vt (B,H,D,N).
        __syncthreads();    // all waves done reading As/Bs fragments
        unsigned short* Tr = &Sh[w * 1152];   // 16 cols x stride 72
        const int bI = (m0 + wm) >> 11, nseq0 = (m0 + wm) & 2047;
        const int colL = lane >> 3;           // 0..7
        const int mL = (lane & 7) * 8;        // 0..56
#pragma unroll
        for (int j = 0; j < 4; ++j) {
            const int col = n0 + wn + j * 16 + l15;
            const float bc = bias[col];
#pragma unroll
            for (int i = 0; i < 4; ++i) {
                uint2 pk;
                pk.x = pk2(acc[i][j][0] + bc, acc[i][j][1] + bc);
                pk.y = pk2(acc[i][j][2] + bc, acc[i][j][3] + bc);
                *(uint2*)&Tr[l15 * 72 + i * 16 + quad * 4] = pk;
            }
            // same-wave DS ops are in-order; reads below see the writes above
#pragma unroll
            for (int p = 0; p < 2; ++p) {
                const int cl = p * 8 + colL;
                uint4 vv = *(const uint4*)&Tr[cl * 72 + mL];
                const int gcol = n0 + wn + j * 16 + cl;
                const int hh = gcol >> 6, dd = gcol & 63;
                *(uint4*)&out[((size_t)(bI * 16 + hh) * 64 + dd) * 2048 + nseq0 + mL] = vv;
            }
        }
    }
}

// ---------------------------------------------------------------- fuse kp + c
// Vectorized (R9). Block = 256 threads = 4 waves; (w>>1) picks the row,
// (w&1) the half-row. Lane handles 8 contiguous bf16 (16B loads).
// head h = col0>>6; dot reduced over the 8-lane group via shfl_xor 1/2/4.
__global__ __launch_bounds__(256) void fuse_kpc(const unsigned short* __restrict__ k,
                                                const unsigned short* __restrict__ pp,
                                                const float* __restrict__ pbu,
                                                const float* __restrict__ pbv,
                                                unsigned short* __restrict__ kp,
                                                float* __restrict__ c) {
    const int t = threadIdx.x;
    const int w = t >> 6, lane = t & 63;
    const int row = blockIdx.x * 2 + (w >> 1);         // row = b*N + n
    const int col0 = (w & 1) * 512 + lane * 8;         // 8 els per lane
    const size_t off = (size_t)row * CC + col0;
    const int h = col0 >> 6;                           // head of this 8-chunk
    const int d0 = col0 & 63;                          // d-offset within head

    bf16x8 kv8 = *(const bf16x8*)&k[off];
    bf16x8 pv8 = *(const bf16x8*)&pp[off];
    bf16x8 s8;
    float val = 0.f;
#pragma unroll
    for (int j = 0; j < 8; ++j) {
        const float kv = bf2f((unsigned short)kv8[j]);
        const float pv = bf2f((unsigned short)pv8[j]);
        s8[j] = (short)f2bf(kv + pv);
        val += pbu[h * 64 + d0 + j] * kv + pbv[h * 64 + d0 + j] * pv;
    }
    *(bf16x8*)&kp[off] = s8;
#pragma unroll
    for (int o = 1; o < 8; o <<= 1) val += __shfl_xor(val, o);
    if ((lane & 7) == 0) {
        const int b = row >> 11, n = row & 2047;
        c[((size_t)(b * HH + h)) * NN + n] = val * SC2E;
    }
}

// ---------------------------------------------------------------- attention
// R2-best shape (75.6us measured): (qt,h,b) -> 128 q rows, 8 waves x 16 q.
// KVBLK=128, double-buffered K/V staging, prefetch after the single per-iter
// barrier. Per tile: two 64-key halves through {QK^T (c-init), exp2, Ps
// roundtrip, PV} reusing s regs / Ps buffer. setprio(1) around MFMA.
__global__ __launch_bounds__(512) void attn_kernel(const unsigned short* __restrict__ q,
                                                   const unsigned short* __restrict__ kp,
                                                   const unsigned short* __restrict__ vt,
                                                   const float* __restrict__ cb,
                                                   unsigned short* __restrict__ att) {
    __shared__ unsigned short Ks[2][128 * 64];   // [key][d], XOR-swizzled
    __shared__ unsigned short Vs[2][64 * 128];   // [d][key], XOR-swizzled
    __shared__ unsigned short Ps[8][16 * 64];    // per-wave P round-trip

    const int t = threadIdx.x;
    const int w = t >> 6, lane = t & 63, l15 = lane & 15, quad = lane >> 4;
    const int qt = blockIdx.x, h = blockIdx.y, b = blockIdx.z;
    const int e3 = l15 & 7;

    // Q fragment: 16 q rows per wave (registers, loaded once)
    bf16x8 qf[2];
    {
        const int qrow = qt * 128 + w * 16 + l15;
        const size_t qoff = ((size_t)(b * NN + qrow) * HH + h) * DD;
#pragma unroll
        for (int c2 = 0; c2 < 2; ++c2)
            qf[c2] = *(const bf16x8*)&q[qoff + c2 * 32 + quad * 8];
    }

    f32x4 oT[4];
    float l_lane = 0.f;
#pragma unroll
    for (int db = 0; db < 4; ++db)
#pragma unroll
        for (int r = 0; r < 4; ++r) oT[db][r] = 0.f;

    const size_t kbase = (size_t)b * NN * CC + (size_t)h * DD;
    const size_t vbase = (size_t)(b * HH + h) * DD * NN;
    const size_t cbase = (size_t)(b * HH + h) * NN;

    // staging maps (kt-invariant): 512 threads x 2 segments, 16B each.
    // K tile: 128 rows x 8 chunks; V tile: 64 d-rows x 16 chunks. XOR
    // pre-swizzle on the GLOBAL chunk (involution; LDS dest stays linear).
    int krow[2], kgc[2], vd[2], vgc[2];
#pragma unroll
    for (int j = 0; j < 2; ++j) {
        const int id = j * 512 + t;
        krow[j] = id >> 3;
        kgc[j] = ((id & 7) ^ (krow[j] & 7)) * 8;
        vd[j] = id >> 4;
        vgc[j] = ((id & 15) ^ (vd[j] & 7)) * 8;
    }

    // prologue: stage kt=0 into buffer 0
#pragma unroll
    for (int j = 0; j < 2; ++j) {
        const int id = j * 512 + t;
        gload_lds16(&kp[kbase + (size_t)krow[j] * CC + kgc[j]], &Ks[0][id * 8]);
        gload_lds16(&vt[vbase + (size_t)vd[j] * NN + vgc[j]], &Vs[0][id * 8]);
    }

    for (int kt = 0; kt < NN / 128; ++kt) {
        const int cur = kt & 1;
        __syncthreads();   // drains prefetch issued last iter (full iter of cover)
        if (kt + 1 < NN / 128) {
#pragma unroll
            for (int j = 0; j < 2; ++j) {
                const int id = j * 512 + t;
                gload_lds16(&kp[kbase + (size_t)((kt + 1) * 128 + krow[j]) * CC + kgc[j]],
                            &Ks[cur ^ 1][id * 8]);
                gload_lds16(&vt[vbase + (size_t)vd[j] * NN + (kt + 1) * 128 + vgc[j]],
                            &Vs[cur ^ 1][id * 8]);
            }
        }

        // c-init for the whole 128-key tile (L2-hot; batched so latency
        // overlaps the first half's ds_reads)
        f32x4 c8r[8];
#pragma unroll
        for (int t8 = 0; t8 < 8; ++t8)
            c8r[t8] = *(const f32x4*)&cb[cbase + kt * 128 + t8 * 16 + quad * 4];

#pragma unroll
        for (int half = 0; half < 2; ++half) {
            // S^T (64 keys x 16 q per wave), c-initialized
            f32x4 s[4];
#pragma unroll
            for (int t4 = 0; t4 < 4; ++t4) s[t4] = c8r[half * 4 + t4];

            __builtin_amdgcn_s_setprio(1);
#pragma unroll
            for (int t4 = 0; t4 < 4; ++t4) {
                const int row = half * 64 + t4 * 16 + l15;
#pragma unroll
                for (int c2 = 0; c2 < 2; ++c2) {
                    bf16x8 kf = *(const bf16x8*)&Ks[cur][row * 64 + (((c2 * 4 + quad) ^ e3) * 8)];
                    s[t4] = __builtin_amdgcn_mfma_f32_16x16x32_bf16(kf, qf[c2], s[t4], 0, 0, 0);
                }
            }
            __builtin_amdgcn_s_setprio(0);

            // fixed-base exp2 softmax; l reduced once at the end
            float rs = 0.f;
#pragma unroll
            for (int t4 = 0; t4 < 4; ++t4)
#pragma unroll
                for (int r = 0; r < 4; ++r) {
                    float pv = exp2f(s[t4][r]);
                    s[t4][r] = pv;
                    rs += pv;
                }
            l_lane += rs;
            // Ps store: XOR-swizzle whole 8-short blocks by (l15&7), no pad.
#pragma unroll
            for (int t4 = 0; t4 < 4; ++t4) {
                uint2 pk;
                pk.x = pk2(s[t4][0], s[t4][1]);
                pk.y = pk2(s[t4][2], s[t4][3]);
                const int blk = t4 * 2 + (quad >> 1);
                *(uint2*)&Ps[w][l15 * 64 + ((blk ^ e3) * 8) + (quad & 1) * 4] = pk;
            }
            // no barrier: Ps[w] wave-private; same-wave DS ops in-order

            // O^T += V^T · P  (keys half*64 .. half*64+63)
            __builtin_amdgcn_s_setprio(1);
#pragma unroll
            for (int c2 = 0; c2 < 2; ++c2) {
                bf16x8 pf = *(const bf16x8*)&Ps[w][l15 * 64 + (((c2 * 4 + quad) ^ e3) * 8)];
#pragma unroll
                for (int db = 0; db < 4; ++db) {
                    bf16x8 vf = *(const bf16x8*)&Vs[cur][(db * 16 + l15) * 128 +
                                                         (((half * 8 + c2 * 4 + quad) ^ e3) * 8)];
                    oT[db] = __builtin_amdgcn_mfma_f32_16x16x32_bf16(vf, pf, oT[db], 0, 0, 0);
                }
            }
            __builtin_amdgcn_s_setprio(0);
        }
    }

    // epilogue: normalize and write bf16 (B,N,H,D)
    float l = l_lane;
    l += __shfl_xor(l, 16);
    l += __shfl_xor(l, 32);
    const float inv = 1.f / l;
    const int qrow = qt * 128 + w * 16 + l15;
    const size_t ob = ((size_t)(b * NN + qrow) * HH + h) * DD;
#pragma unroll
    for (int db = 0; db < 4; ++db) {
        uint2 pk;
        pk.x = pk2(oT[db][0] * inv, oT[db][1] * inv);
        pk.y = pk2(oT[db][2] * inv, oT[db][3] * inv);
        *(uint2*)&att[ob + db * 16 + quad * 4] = pk;
    }
}

// ---------------------------------------------------------------- out GEMM
// out fp32 = att·Wo^T + bo. 128x64 tile -> 512 blocks = 2/CU.
// R10: BK=64 (16 K-iters, was 32) as two [*][32] slabs; 24KB LDS.
__global__ __launch_bounds__(256) void gemm_out(const unsigned short* __restrict__ A,
                                                const unsigned short* __restrict__ B,
                                                float* __restrict__ out,
                                                const float* __restrict__ bias) {
    constexpr int K = CC;
    __shared__ unsigned short As[128 * 64];   // two [128][32] slabs
    __shared__ unsigned short Bs[64 * 64];    // two [64][32] slabs
    const int t = threadIdx.x;
    const int w = t >> 6, lane = t & 63, l15 = lane & 15, quad = lane >> 4;
    const int m0 = blockIdx.x * 128, n0 = blockIdx.y * 64;
    const int wm = (w >> 1) * 64, wn = (w & 1) * 32;

    f32x4 acc[4][2];
#pragma unroll
    for (int i = 0; i < 4; ++i)
#pragma unroll
        for (int j = 0; j < 2; ++j)
#pragma unroll
            for (int r = 0; r < 4; ++r) acc[i][j][r] = 0.f;

    for (int kb = 0; kb < K; kb += 64) {
        __syncthreads();
        // A: 128x64 = 1024 16B chunks (256 threads x 4)
#pragma unroll
        for (int j = 0; j < 4; ++j) {
            const int id = j * 256 + t;
            const int half = id >> 9, id9 = id & 511;
            const int row = id9 >> 2, c4 = (id9 & 3) * 8;
            gload_lds16(&A[(size_t)(m0 + row) * K + kb + half * 32 + c4],
                        &As[half * 4096 + id9 * 8]);
        }
        // B: 64x64 = 512 16B chunks (256 threads x 2)
#pragma unroll
        for (int j = 0; j < 2; ++j) {
            const int id = j * 256 + t;
            const int half = id >> 8, id8 = id & 255;
            const int row = id8 >> 2, c4 = (id8 & 3) * 8;
            gload_lds16(&B[(size_t)(n0 + row) * K + kb + half * 32 + c4],
                        &Bs[half * 2048 + id8 * 8]);
        }
        __syncthreads();
#pragma unroll
        for (int kk = 0; kk < 2; ++kk) {
            bf16x8 af[4], bfr[2];
#pragma unroll
            for (int i = 0; i < 4; ++i)
                af[i] = *(const bf16x8*)&As[kk * 4096 + (wm + i * 16 + l15) * 32 + quad * 8];
#pragma unroll
            for (int j = 0; j < 2; ++j)
                bfr[j] = *(const bf16x8*)&Bs[kk * 2048 + (wn + j * 16 + l15) * 32 + quad * 8];
#pragma unroll
            for (int i = 0; i < 4; ++i)
#pragma unroll
                for (int j = 0; j < 2; ++j)
                    acc[i][j] = __builtin_amdgcn_mfma_f32_16x16x32_bf16(af[i], bfr[j], acc[i][j], 0, 0, 0);
        }
    }

#pragma unroll
    for (int i = 0; i < 4; ++i)
#pragma unroll
        for (int j = 0; j < 2; ++j) {
            const int col = n0 + wn + j * 16 + l15;
            const int row_base = m0 + wm + i * 16 + quad * 4;
            const float bc = bias[col];
#pragma unroll
            for (int r = 0; r < 4; ++r)
                out[(size_t)(row_base + r) * CC + col] = acc[i][j][r] + bc;
        }
}

// ---------------------------------------------------------------- launch
extern "C" void kernel_launch(void* const* d_in, const int* in_sizes, int n_in,
                              void* d_out, int out_size, void* d_ws, size_t ws_size,
                              hipStream_t stream) {
    const float* hs   = (const float*)d_in[0];
    const float* pos  = (const float*)d_in[1];
    const float* Wq   = (const float*)d_in[2];
    const float* bq   = (const float*)d_in[3];
    const float* Wk   = (const float*)d_in[4];
    const float* bk   = (const float*)d_in[5];
    const float* Wv   = (const float*)d_in[6];
    const float* bv   = (const float*)d_in[7];
    const float* Wpos = (const float*)d_in[8];
    const float* pbu  = (const float*)d_in[9];
    const float* pbv  = (const float*)d_in[10];
    const float* Wo   = (const float*)d_in[11];
    const float* bo   = (const float*)d_in[12];
    float* out = (float*)d_out;

    const size_t nHS = (size_t)MM * CC;
    const size_t nW  = (size_t)CC * CC;

    unsigned short* p = (unsigned short*)d_ws;
    unsigned short* hsb  = p;            p += nHS;
    unsigned short* posb = p;            p += nHS;
    unsigned short* wqb  = p;            p += nW;
    unsigned short* wkb  = p;            p += nW;
    unsigned short* wvb  = p;            p += nW;
    unsigned short* wpb  = p;            p += nW;
    unsigned short* wob  = p;            p += nW;
    unsigned short* qsb  = p;            p += nHS;
    unsigned short* kbf  = p;            p += nHS;
    unsigned short* pbf  = p;            p += nHS;
    unsigned short* kpb  = p;            p += nHS;
    unsigned short* vtb  = p;            p += nHS;
    float* cb = (float*)p;               p += (size_t)BB * HH * NN * 2;
    unsigned short* attb = hsb;          // alias: hsb dead after gemm_qkvp

    CastArgs ca;
    ca.src[0] = hs;   ca.dst[0] = hsb;
    ca.src[1] = pos;  ca.dst[1] = posb;
    ca.src[2] = Wq;   ca.dst[2] = wqb;
    ca.src[3] = Wk;   ca.dst[3] = wkb;
    ca.src[4] = Wv;   ca.dst[4] = wvb;
    ca.src[5] = Wpos; ca.dst[5] = wpb;
    ca.src[6] = Wo;   ca.dst[6] = wob;
    cast_all<<<13312, 256, 0, stream>>>(ca);   // 2*4096 + 5*1024, exact

    GemmBatch gb;
    gb.A[0] = hsb;  gb.B[0] = wqb; gb.out[0] = qsb; gb.bias[0] = bq;
    gb.A[1] = hsb;  gb.B[1] = wkb; gb.out[1] = kbf; gb.bias[1] = bk;
    gb.A[2] = hsb;  gb.B[2] = wvb; gb.out[2] = vtb; gb.bias[2] = bv;
    gb.A[3] = posb; gb.B[3] = wpb; gb.out[3] = pbf; gb.bias[3] = nullptr;
    dim3 ggrid(MM / 128, CC / 128, 4);
    gemm_qkvp<<<ggrid, 256, 0, stream>>>(gb);

    fuse_kpc<<<MM / 2, 256, 0, stream>>>(kbf, pbf, pbu, pbv, kpb, cb);

    dim3 agrid(NN / 128, HH, BB);
    attn_kernel<<<agrid, 512, 0, stream>>>(qsb, kpb, vtb, cb, attb);

    dim3 ogrid(MM / 128, CC / 64);
    gemm_out<<<ogrid, 256, 0, stream>>>(attb, wob, out, bo);
}